// Round 1
// baseline (852.409 us; speedup 1.0000x reference)
//
#include <hip/hip_runtime.h>
#include <math.h>

#define BN 8
#define TN 1024
#define HN 192
#define NHN 2
#define KCN 96
#define LN 6
#define FFNN 768
#define OUTN 192
#define QSTR 104  // kt/rbt LDS row stride in shorts: 13 granules (odd) -> conflict-free b128
#define GSTR 200  // k_g192 LDS row stride (192 data + pad): 25 granules (odd)
#define M0S 12.0f // fixed softmax shift: scores are O(1); exp(s-12) safe to s~100

typedef short bfrag __attribute__((ext_vector_type(8)));
typedef float f32x4 __attribute__((ext_vector_type(4)));

__device__ __forceinline__ short f2bf(float f) {
    union { float f; unsigned u; } v; v.f = f;
    unsigned r = v.u + 0x7fffu + ((v.u >> 16) & 1u);
    return (short)(r >> 16);
}
__device__ __forceinline__ float bf2f(short s) {
    union { unsigned u; float f; } v;
    v.u = ((unsigned)(unsigned short)s) << 16;
    return v.f;
}
__device__ __forceinline__ int pack2(float a, float b) {
    return (int)(unsigned short)f2bf(a) | (((int)(unsigned short)f2bf(b)) << 16);
}

#define QSCALE 0.10206207261596575f  // 1/sqrt(96)

// ---------------------------------------------------------------------------
// Fused weight conversions (one launch). Index ranges:
// [0,N0)   qkv fused weights -> wqkv [L][576][192], q rows pre-scaled
// [.,+N1)  qkv bias -> bqkv [L][576]
// [.,+N2)  o-proj -> wo16
// [.,+N3)  stats proj -> wp16
// [.,+N4)  f1 conv [L][M][C][3] -> [L][3][M][C]
// [.,+N4)  f2 conv likewise
// ---------------------------------------------------------------------------
__global__ void k_cvtall(const float* __restrict__ qw, const float* __restrict__ kw,
        const float* __restrict__ vw, const float* __restrict__ qb,
        const float* __restrict__ kb, const float* __restrict__ vb,
        const float* __restrict__ ow, const float* __restrict__ pw,
        const float* __restrict__ f1w, const float* __restrict__ f2w,
        short* __restrict__ wqkv, float* __restrict__ bqkv,
        short* __restrict__ wo16, short* __restrict__ wp16,
        short* __restrict__ wf1, short* __restrict__ wf2) {
    const int N0 = LN * 576 * 192;
    const int N1 = LN * 576;
    const int N2 = LN * HN * HN;
    const int N3 = 2 * OUTN * HN;
    const int N4 = LN * FFNN * HN * 3;
    int i = blockIdx.x * 256 + threadIdx.x;
    if (i < N0) {
        int c = i % 192, r = (i / 192) % 576, l = i / (192 * 576);
        float val, sc = 1.f;
        if (r < 192) { val = qw[((size_t)l * 192 + r) * 192 + c]; sc = QSCALE; }
        else if (r < 384) val = kw[((size_t)l * 192 + (r - 192)) * 192 + c];
        else val = vw[((size_t)l * 192 + (r - 384)) * 192 + c];
        wqkv[i] = f2bf(val * sc);
        return;
    }
    i -= N0;
    if (i < N1) {
        int r = i % 576, l = i / 576;
        bqkv[i] = (r < 192) ? qb[l * 192 + r] * QSCALE
                : (r < 384) ? kb[l * 192 + r - 192]
                            : vb[l * 192 + r - 384];
        return;
    }
    i -= N1;
    if (i < N2) { wo16[i] = f2bf(ow[i]); return; }
    i -= N2;
    if (i < N3) { wp16[i] = f2bf(pw[i]); return; }
    i -= N3;
    if (i < N4) {
        int tap = i % 3, c = (i / 3) % HN, m = (i / (3 * HN)) % FFNN, l = i / (3 * HN * FFNN);
        wf1[(((size_t)l * 3 + tap) * FFNN + m) * HN + c] = f2bf(f1w[i]);
        return;
    }
    i -= N4;
    if (i < N4) {
        int tap = i % 3, c = (i / 3) % FFNN, m = (i / (3 * FFNN)) % HN, l = i / (3 * FFNN * HN);
        wf2[(((size_t)l * 3 + tap) * HN + m) * FFNN + c] = f2bf(f2w[i]);
    }
}

// ---------------------------------------------------------------------------
// Embedding: x fp32 ch-major (B,H,T) + xb bf16 t-major (B,T,H), both masked.
// ---------------------------------------------------------------------------
__global__ __launch_bounds__(256) void k_embed(const int* __restrict__ tok,
        const int* __restrict__ lens, const float* __restrict__ emb,
        float* __restrict__ x, short* __restrict__ xb) {
    __shared__ float s[HN][65];
    const int b = blockIdx.y, t0 = blockIdx.x * 64, tid = threadIdx.x;
    const int len = lens[b];
    for (int idx = tid; idx < 64 * HN; idx += 256) {
        int tt = idx / HN, c = idx % HN;
        int t = t0 + tt;
        float v = 0.f;
        if (t < len) v = emb[tok[b * TN + t] * HN + c] * 13.856406460551018f; // sqrt(192)
        s[c][tt] = v;
    }
    __syncthreads();
    for (int idx = tid; idx < 64 * HN; idx += 256) {
        int c = idx >> 6, tt = idx & 63;
        x[((size_t)b * HN + c) * TN + t0 + tt] = s[c][tt];
    }
    for (int idx = tid; idx < 64 * 96; idx += 256) {
        int tt = idx / 96, p = idx % 96;
        ((int*)xb)[((size_t)(b * TN + t0 + tt)) * 96 + p] = pack2(s[2 * p][tt], s[2 * p + 1][tt]);
    }
}

// ---------------------------------------------------------------------------
// Single-stage K=192 GEMM (o-proj with fused attention-partial merge; stats).
// Masked tiles: MERGE -> plain return (stale yf never observable);
// MASK_OUT (stats) -> exact-zero fill (k_final requires it).
// ---------------------------------------------------------------------------
template <bool MERGE, bool MASK_OUT>
__global__ __launch_bounds__(256) void k_g192(
        const short* __restrict__ W, const short* __restrict__ X,
        const float* __restrict__ bias, float* __restrict__ Y,
        const short* __restrict__ accP, const float* __restrict__ lPp,
        const int* __restrict__ lens, int M) {
    __shared__ short Wt[64 * GSTR];
    __shared__ short Xt[64 * GSTR];
    __shared__ float linv[128];
    const int b = blockIdx.z, m0 = blockIdx.y * 64, t0 = blockIdx.x * 64;
    const int len = lens[b];
    const int tid = threadIdx.x;
    const int w = tid >> 6, lane = tid & 63, col = lane & 15, quad = lane >> 4;

    if (t0 >= len) {
        if (MASK_OUT) {
            const int mbase = m0 + w * 16 + quad * 4;
#pragma unroll
            for (int st = 0; st < 4; ++st) {
                int t = t0 + st * 16 + col;
#pragma unroll
                for (int reg = 0; reg < 4; ++reg)
                    Y[((size_t)b * M + mbase + reg) * TN + t] = 0.f;
            }
        }
        return;
    }

    if (MERGE) {
        if (tid < 128) {
            int tt = tid & 63, h = tid >> 6;
            float l = 0.f;
#pragma unroll
            for (int sh = 0; sh < 4; ++sh)
                l += lPp[(((size_t)sh * BN + b) * NHN + h) * TN + t0 + tt];
            linv[tid] = (l > 0.f) ? 1.f / l : 0.f;
        }
        __syncthreads();
    }
    for (int i = tid; i < 1536; i += 256) {
        int mm = i / 24, part = i % 24;
        *(int4*)(Wt + mm * GSTR + part * 8) =
            *(const int4*)(W + ((size_t)(m0 + mm)) * 192 + part * 8);
    }
    for (int i = tid; i < 1536; i += 256) {
        int tt = i / 24, part = i % 24;
        if (!MERGE) {
            *(int4*)(Xt + tt * GSTR + part * 8) =
                *(const int4*)(X + ((size_t)(b * TN + t0 + tt)) * 192 + part * 8);
        } else {
            const size_t base = ((size_t)(b * TN + t0 + tt)) * 192 + part * 8;
            const size_t HSq = (size_t)BN * TN * HN;
            float a[8];
#pragma unroll
            for (int c = 0; c < 8; ++c) a[c] = 0.f;
#pragma unroll
            for (int sh = 0; sh < 4; ++sh) {
                int4 v = *(const int4*)(accP + sh * HSq + base);
                const short* sv = (const short*)&v;
#pragma unroll
                for (int c = 0; c < 8; ++c) a[c] += bf2f(sv[c]);
            }
            float li = linv[(part >= 12 ? 64 : 0) + tt];
            int4 o;
            int* oi = (int*)&o;
#pragma unroll
            for (int c = 0; c < 4; ++c) oi[c] = pack2(a[2 * c] * li, a[2 * c + 1] * li);
            *(int4*)(Xt + tt * GSTR + part * 8) = o;
        }
    }
    __syncthreads();

    f32x4 acc[4];
#pragma unroll
    for (int st = 0; st < 4; ++st) acc[st] = (f32x4){0.f, 0.f, 0.f, 0.f};
#pragma unroll
    for (int ks = 0; ks < 6; ++ks) {
        bfrag af = *(const bfrag*)(Wt + (w * 16 + col) * GSTR + ks * 32 + quad * 8);
#pragma unroll
        for (int st = 0; st < 4; ++st) {
            bfrag bf = *(const bfrag*)(Xt + (st * 16 + col) * GSTR + ks * 32 + quad * 8);
            acc[st] = __builtin_amdgcn_mfma_f32_16x16x32_bf16(af, bf, acc[st], 0, 0, 0);
        }
    }

    const int mbase = m0 + w * 16 + quad * 4;
    float bs[4];
#pragma unroll
    for (int reg = 0; reg < 4; ++reg) bs[reg] = bias[mbase + reg];
#pragma unroll
    for (int st = 0; st < 4; ++st) {
        int t = t0 + st * 16 + col;
        bool om = MASK_OUT && (t >= len);
#pragma unroll
        for (int reg = 0; reg < 4; ++reg) {
            float u = acc[st][reg] + bs[reg];
            if (om) u = 0.f;
            Y[((size_t)b * M + mbase + reg) * TN + t] = u;
        }
    }
}

// ---------------------------------------------------------------------------
// Single-stage fused QKV projection. Masked t-tiles: zero-fill q and v
// (q rows must be finite for attention; v multiplies exact-0 p but stale
// bytes could be bf16-NaN since this region overlays fp32 partials);
// k blocks return (scores at masked s are unconditionally set to -1e4).
// ---------------------------------------------------------------------------
__global__ __launch_bounds__(256) void k_qkv2(
        const short* __restrict__ W, const short* __restrict__ X,
        const float* __restrict__ bias, short* __restrict__ qo,
        short* __restrict__ ko, short* __restrict__ vo,
        const int* __restrict__ lens) {
    __shared__ short Wt[64 * GSTR];
    __shared__ short Xt[64 * GSTR];
    const int b = blockIdx.z, m0 = blockIdx.y * 64, t0 = blockIdx.x * 64;
    const int len = lens[b];
    const int tid = threadIdx.x;
    const int w = tid >> 6, lane = tid & 63, col = lane & 15, quad = lane >> 4;
    const int proj = m0 / 192;           // block-uniform: 0=q 1=k 2=v
    const int mbase = m0 + w * 16 + quad * 4;
    const int mloc = mbase - proj * 192;

    if (t0 >= len) {
        if (proj == 1) return;
#pragma unroll
        for (int st = 0; st < 4; ++st) {
            int t = t0 + st * 16 + col;
            if (proj == 0) {
                int2 z = {0, 0};
                *(int2*)(qo + ((size_t)(b * TN + t)) * 192 + mloc) = z;
            } else {
#pragma unroll
                for (int reg = 0; reg < 4; ++reg)
                    vo[((size_t)b * 192 + mloc + reg) * TN + t] = 0;
            }
        }
        return;
    }

    for (int i = tid; i < 1536; i += 256) {
        int mm = i / 24, part = i % 24;
        *(int4*)(Wt + mm * GSTR + part * 8) =
            *(const int4*)(W + ((size_t)(m0 + mm)) * 192 + part * 8);
    }
    for (int i = tid; i < 1536; i += 256) {
        int tt = i / 24, part = i % 24;
        *(int4*)(Xt + tt * GSTR + part * 8) =
            *(const int4*)(X + ((size_t)(b * TN + t0 + tt)) * 192 + part * 8);
    }
    __syncthreads();

    f32x4 acc[4];
#pragma unroll
    for (int st = 0; st < 4; ++st) acc[st] = (f32x4){0.f, 0.f, 0.f, 0.f};
#pragma unroll
    for (int ks = 0; ks < 6; ++ks) {
        bfrag af = *(const bfrag*)(Wt + (w * 16 + col) * GSTR + ks * 32 + quad * 8);
#pragma unroll
        for (int st = 0; st < 4; ++st) {
            bfrag bf = *(const bfrag*)(Xt + (st * 16 + col) * GSTR + ks * 32 + quad * 8);
            acc[st] = __builtin_amdgcn_mfma_f32_16x16x32_bf16(af, bf, acc[st], 0, 0, 0);
        }
    }

    float bs[4];
#pragma unroll
    for (int reg = 0; reg < 4; ++reg) bs[reg] = bias[mbase + reg];
#pragma unroll
    for (int st = 0; st < 4; ++st) {
        int t = t0 + st * 16 + col;
        float v[4];
#pragma unroll
        for (int reg = 0; reg < 4; ++reg) v[reg] = acc[st][reg] + bs[reg];
        if (proj < 2) {
            short* dst = (proj == 0) ? qo : ko;
            int2 pk;
            pk.x = pack2(v[0], v[1]);
            pk.y = pack2(v[2], v[3]);
            *(int2*)(dst + ((size_t)(b * TN + t)) * 192 + mloc) = pk;
        } else {
#pragma unroll
            for (int reg = 0; reg < 4; ++reg)
                vo[((size_t)b * 192 + mloc + reg) * TN + t] = f2bf(v[reg]);
        }
    }
}

// ---------------------------------------------------------------------------
// MFMA bf16 conv (f1, f2). Masked t-tiles: zero-fill output, skip compute.
// ---------------------------------------------------------------------------
template <int TAPS, int TT, bool RELU, bool MASK_OUT, int OUTK, int KSPLIT>
__global__ __launch_bounds__(256) void k_mgemm(
        const short* __restrict__ W, const short* __restrict__ X,
        const float* __restrict__ bias, void* __restrict__ Yv,
        float* __restrict__ Yv2, float* __restrict__ Yv3,
        const int* __restrict__ lens, int M, int Cin) {
    constexpr int P = (TAPS - 1) / 2;
    constexpr int NST = TT / 16;
    __shared__ short Wt[TAPS][64][72];
    __shared__ short Xt[TT + 2 * P][72];

    const int b = blockIdx.z;
    const int mtiles = gridDim.y / KSPLIT;
    const int kg = blockIdx.y / mtiles;
    const int m0 = (blockIdx.y % mtiles) * 64;
    const int t0 = blockIdx.x * TT;
    const int len = lens[b];
    const int tid = threadIdx.x;
    const int w = tid >> 6;
    const int lane = tid & 63;
    const int col = lane & 15;
    const int quad = lane >> 4;
    const int mbase = m0 + w * 16 + quad * 4;

    if (MASK_OUT && t0 >= len) {
#pragma unroll
        for (int st = 0; st < NST; ++st) {
            int t = t0 + st * 16 + col;
            if (OUTK == 0) {
                float* dst = (KSPLIT > 1) ? (kg == 0 ? (float*)Yv : (kg == 1 ? Yv2 : Yv3))
                                          : (float*)Yv;
#pragma unroll
                for (int reg = 0; reg < 4; ++reg)
                    dst[((size_t)b * M + mbase + reg) * TN + t] = 0.f;
            } else {
                int2 z = {0, 0};
                *(int2*)((short*)Yv + ((size_t)(b * TN + t)) * M + mbase) = z;
            }
        }
        return;
    }

    f32x4 acc[NST];
#pragma unroll
    for (int st = 0; st < NST; ++st) acc[st] = (f32x4){0.f, 0.f, 0.f, 0.f};

    const int cspan = Cin / KSPLIT;
    const int cbeg = kg * cspan;
    const int cend = cbeg + cspan;
    for (int c0 = cbeg; c0 < cend; c0 += 64) {
        __syncthreads();
        for (int i = tid; i < TAPS * 64 * 8; i += 256) {
            int tap = i / (64 * 8);
            int mm = (i / 8) & 63;
            int part = i & 7;
            *(int4*)(&Wt[tap][mm][part * 8]) =
                *(const int4*)(W + ((size_t)tap * M + m0 + mm) * Cin + c0 + part * 8);
        }
        for (int i = tid; i < (TT + 2 * P) * 8; i += 256) {
            int tt = i >> 3;
            int part = i & 7;
            int t = t0 + tt - P;
            int4 v = {0, 0, 0, 0};
            if (t >= 0 && t < TN)
                v = *(const int4*)(X + ((size_t)b * TN + t) * Cin + c0 + part * 8);
            *(int4*)(&Xt[tt][part * 8]) = v;
        }
        __syncthreads();
#pragma unroll
        for (int ks = 0; ks < 2; ++ks) {
#pragma unroll
            for (int tap = 0; tap < TAPS; ++tap) {
                bfrag af = *(const bfrag*)(&Wt[tap][w * 16 + col][ks * 32 + quad * 8]);
#pragma unroll
                for (int st = 0; st < NST; ++st) {
                    bfrag bf = *(const bfrag*)(&Xt[st * 16 + col + tap][ks * 32 + quad * 8]);
                    acc[st] = __builtin_amdgcn_mfma_f32_16x16x32_bf16(af, bf, acc[st], 0, 0, 0);
                }
            }
        }
    }

    float bs[4];
#pragma unroll
    for (int reg = 0; reg < 4; ++reg)
        bs[reg] = (KSPLIT > 1 && kg) ? 0.f : bias[mbase + reg];
#pragma unroll
    for (int st = 0; st < NST; ++st) {
        int t = t0 + st * 16 + col;
        bool om = MASK_OUT && (t >= len);
        float v[4];
#pragma unroll
        for (int reg = 0; reg < 4; ++reg) {
            float u = acc[st][reg] + bs[reg];
            if (RELU) u = fmaxf(u, 0.f);
            if (om) u = 0.f;
            v[reg] = u;
        }
        if (OUTK == 0) {
            float* dst = (KSPLIT > 1) ? (kg == 0 ? (float*)Yv : (kg == 1 ? Yv2 : Yv3))
                                      : (float*)Yv;
#pragma unroll
            for (int reg = 0; reg < 4; ++reg)
                dst[((size_t)b * M + mbase + reg) * TN + t] = v[reg];
        } else {
            int2 pk;
            pk.x = pack2(v[0], v[1]);
            pk.y = pack2(v[2], v[3]);
            *(int2*)((short*)Yv + ((size_t)(b * TN + t)) * M + mbase) = pk;
        }
    }
}

// ---------------------------------------------------------------------------
// MFMA bf16 flash attention, partial-sum formulation (R7 notes).
// Masked q-tiles: write lP=0 (merge linv=0 kills stale accP) and return.
// ---------------------------------------------------------------------------
__global__ __launch_bounds__(512, 4) void k_attn4(
        const short* __restrict__ Q, const short* __restrict__ K,
        const short* __restrict__ V, const float* __restrict__ relk,
        const float* __restrict__ relv, short* __restrict__ accP,
        float* __restrict__ lP, const int* __restrict__ lens) {
    __shared__ short kt[64 * QSTR];
    __shared__ short vt[96 * 72];
    __shared__ short Pt[128 * 72];
    __shared__ short rbt[16 * QSTR];   // relk as bf16 B-tile (rows 9..15 zero)
    __shared__ float rels[128 * 12];
    __shared__ float sband[128 * 12];
    __shared__ float rvs[9 * 96];

    const int b = blockIdx.z;
    const int h = blockIdx.y >> 2, sh = blockIdx.y & 3;
    const int t0 = blockIdx.x * 128;
    const int len = lens[b];
    const int tid = threadIdx.x;
    const int w = tid >> 6;
    const int lane = tid & 63;
    const int col = lane & 15;
    const int quad = lane >> 4;

    if (t0 >= len) {
        if (tid < 128)
            lP[(((size_t)sh * BN + b) * NHN + h) * TN + t0 + tid] = 0.f;
        return;
    }

    const short* Qb = Q + ((size_t)b * TN + t0) * HN + h * KCN;
    const short* Kb = K + ((size_t)b * TN + sh * 256) * HN + h * KCN;
    const short* Vb = V + ((size_t)b * HN + h * KCN) * TN + sh * 256;

    bfrag qf[3];
#pragma unroll
    for (int ks = 0; ks < 3; ++ks)
        qf[ks] = *(const bfrag*)(Qb + (size_t)(w * 16 + col) * HN + ks * 32 + quad * 8);

    for (int i = tid; i < 9 * 96; i += 512) rvs[i] = relv[i];
    for (int i = tid; i < 16 * 96; i += 512) {
        int r = i / 96, c = i % 96;
        rbt[r * QSTR + c] = (r < 9) ? f2bf(relk[r * 96 + c]) : (short)0;
    }
    for (int i = tid; i < 128 * 12; i += 512) sband[i] = -1e30f;
    __syncthreads();

    {
        f32x4 rc = (f32x4){0.f, 0.f, 0.f, 0.f};
#pragma unroll
        for (int ks = 0; ks < 3; ++ks) {
            bfrag bf = *(const bfrag*)(rbt + col * QSTR + ks * 32 + quad * 8);
            rc = __builtin_amdgcn_mfma_f32_16x16x32_bf16(qf[ks], bf, rc, 0, 0, 0);
        }
        if (col < 12) {
#pragma unroll
            for (int reg = 0; reg < 4; ++reg)
                rels[(w * 16 + quad * 4 + reg) * 12 + col] = rc[reg];
        }
    }

    float lsum[4];
    f32x4 accv[6];
#pragma unroll
    for (int r = 0; r < 4; ++r) lsum[r] = 0.f;
#pragma unroll
    for (int n = 0; n < 6; ++n) accv[n] = (f32x4){0.f, 0.f, 0.f, 0.f};

    const int rem = len - sh * 256;
    const int nj = (rem <= 0) ? 0 : ((rem >= 256) ? 4 : ((rem + 63) >> 6));

    for (int j = 0; j < nj; ++j) {
        const int s0g = sh * 256 + j * 64;
        __syncthreads();
        for (int i = tid; i < 768; i += 512) {
            int row = i / 12, part = i % 12;
            *(int4*)(kt + row * QSTR + part * 8) =
                *(const int4*)(Kb + ((size_t)(j * 64 + row)) * HN + part * 8);
        }
        for (int i = tid; i < 768; i += 512) {
            int c = i >> 3, part = i & 7;
            *(int4*)(vt + c * 72 + part * 8) =
                *(const int4*)(Vb + (size_t)c * TN + j * 64 + part * 8);
        }
        __syncthreads();

        f32x4 sacc[4];
#pragma unroll
        for (int st = 0; st < 4; ++st) sacc[st] = (f32x4){0.f, 0.f, 0.f, 0.f};
#pragma unroll
        for (int ks = 0; ks < 3; ++ks) {
#pragma unroll
            for (int st = 0; st < 4; ++st) {
                bfrag bf = *(const bfrag*)(kt + (st * 16 + col) * QSTR + ks * 32 + quad * 8);
                sacc[st] = __builtin_amdgcn_mfma_f32_16x16x32_bf16(qf[ks], bf, sacc[st], 0, 0, 0);
            }
        }

#pragma unroll
        for (int reg = 0; reg < 4; ++reg) {
            const int lq = w * 16 + quad * 4 + reg;
            const int qg = t0 + lq;
#pragma unroll
            for (int st = 0; st < 4; ++st) {
                int sg = s0g + st * 16 + col;
                float v = sacc[st][reg];
                int d = sg - qg + 4;
                bool inb = (d >= 0) && (d <= 8);
                if (inb) v += rels[lq * 12 + d];
                if (sg >= len) v = -1e4f;
                if (inb) sband[lq * 12 + d] = v;
                float p = __expf(v - M0S);
                lsum[reg] += p;
                Pt[lq * 72 + st * 16 + col] = f2bf(p);
            }
        }
#pragma unroll
        for (int ks = 0; ks < 2; ++ks) {
            bfrag af = *(const bfrag*)(Pt + (w * 16 + col) * 72 + ks * 32 + quad * 8);
#pragma unroll
            for (int nt = 0; nt < 6; ++nt) {
                bfrag bf = *(const bfrag*)(vt + (nt * 16 + col) * 72 + ks * 32 + quad * 8);
                accv[nt] = __builtin_amdgcn_mfma_f32_16x16x32_bf16(af, bf, accv[nt], 0, 0, 0);
            }
        }
    }

#pragma unroll
    for (int reg = 0; reg < 4; ++reg) {
        lsum[reg] += __shfl_xor(lsum[reg], 1);
        lsum[reg] += __shfl_xor(lsum[reg], 2);
        lsum[reg] += __shfl_xor(lsum[reg], 4);
        lsum[reg] += __shfl_xor(lsum[reg], 8);
    }
    __syncthreads();

    short* aout = accP + (size_t)sh * BN * TN * HN;
#pragma unroll
    for (int reg = 0; reg < 4; ++reg) {
        const int lq = w * 16 + quad * 4 + reg;
        const int qg = t0 + lq;
        float pb[9];
#pragma unroll
        for (int d = 0; d < 9; ++d)
            pb[d] = __expf(sband[lq * 12 + d] - M0S);
#pragma unroll
        for (int nt = 0; nt < 6; ++nt) {
            int c = nt * 16 + col;
            float r = accv[nt][reg];
#pragma unroll
            for (int d = 0; d < 9; ++d) r += pb[d] * rvs[d * 96 + c];
            aout[((size_t)(b * TN + qg)) * HN + h * KCN + c] = f2bf(r);
        }
        if (col == 0)
            lP[(((size_t)sh * BN + b) * NHN + h) * TN + qg] = lsum[reg];
    }
}

// ---------------------------------------------------------------------------
// Residual + LayerNorm: x = LN(x + y [+ y2 [+ y3]])*g + b, fp32 in-place;
// masked bf16 t-major copy xb. Fully-masked tiles: zero xb only (x is dead).
// ---------------------------------------------------------------------------
template <int NADD>
__global__ __launch_bounds__(256) void k_ln(float* __restrict__ x,
        const float* __restrict__ y, const float* __restrict__ y2,
        const float* __restrict__ y3, const float* __restrict__ g,
        const float* __restrict__ bb, short* __restrict__ xb,
        const int* __restrict__ lens) {
    __shared__ float s[HN][33];
    __shared__ float red1[256], red2[256];
    __shared__ float mu[32], rs[32];
    const int b = blockIdx.y;
    const int t0 = blockIdx.x * 32;
    const int tid = threadIdx.x;
    const int len = lens[b];

    if (t0 >= len) {
        for (int idx = tid; idx < 32 * 96; idx += 256)
            ((int*)xb)[((size_t)(b * TN + t0 + idx / 96)) * 96 + idx % 96] = 0;
        return;
    }

    for (int idx = tid; idx < HN * 32; idx += 256) {
        int c = idx >> 5, tt = idx & 31;
        size_t gi = ((size_t)b * HN + c) * TN + t0 + tt;
        float v = x[gi] + y[gi];
        if (NADD >= 2) v += y2[gi];
        if (NADD >= 3) v += y3[gi];
        s[c][tt] = v;
    }
    __syncthreads();
    int tt = tid & 31, grp = tid >> 5;  // 8 groups x 24 channels
    float sum = 0.f, sum2 = 0.f;
    for (int c = grp * 24; c < grp * 24 + 24; ++c) {
        float v = s[c][tt];
        sum += v;
        sum2 += v * v;
    }
    red1[tid] = sum;
    red2[tid] = sum2;
    __syncthreads();
    if (tid < 32) {
        float tot = 0.f, tot2 = 0.f;
#pragma unroll
        for (int gg = 0; gg < 8; ++gg) { tot += red1[gg * 32 + tid]; tot2 += red2[gg * 32 + tid]; }
        float mean = tot / (float)HN;
        float var = tot2 / (float)HN - mean * mean;
        mu[tid] = mean;
        rs[tid] = rsqrtf(var + 1e-5f);
    }
    __syncthreads();
    for (int idx = tid; idx < HN * 32; idx += 256) {
        int c = idx >> 5, t2 = idx & 31;
        float v = (s[c][t2] - mu[t2]) * rs[t2] * g[c] + bb[c];
        x[((size_t)b * HN + c) * TN + t0 + t2] = v;
    }
    for (int idx = tid; idx < 32 * 96; idx += 256) {
        int t2 = idx / 96, p = idx % 96;
        int c0 = 2 * p;
        float v0 = (s[c0][t2] - mu[t2]) * rs[t2] * g[c0] + bb[c0];
        float v1 = (s[c0 + 1][t2] - mu[t2]) * rs[t2] * g[c0 + 1] + bb[c0 + 1];
        if (t0 + t2 >= len) { v0 = 0.f; v1 = 0.f; }
        ((int*)xb)[((size_t)(b * TN + t0 + t2)) * 96 + p] = pack2(v0, v1);
    }
}

// ---------------------------------------------------------------------------
// Final: z = m + eps*exp(logs)*mask ; outputs (z, m, logs, x*mask, mask)
// ---------------------------------------------------------------------------
__global__ void k_final(const float* __restrict__ stats, const float* __restrict__ x,
        const float* __restrict__ eps, const int* __restrict__ lens,
        float* __restrict__ out) {
    int idx = blockIdx.x * 256 + threadIdx.x;
    int t = idx % TN;
    int o = (idx / TN) % OUTN;
    int b = idx / (TN * OUTN);
    float maskv = (t < lens[b]) ? 1.f : 0.f;
    const size_t S = (size_t)BN * OUTN * TN;
    float m = stats[((size_t)(b * 2 * OUTN) + o) * TN + t];
    float ls = stats[((size_t)(b * 2 * OUTN) + OUTN + o) * TN + t];
    float e = eps[idx];
    out[idx] = m + e * expf(ls) * maskv;
    out[S + idx] = m;
    out[2 * S + idx] = ls;
    out[3 * S + idx] = x[idx] * maskv;
    if (o == 0) out[4 * S + (size_t)b * TN + t] = maskv;
}

// ---------------------------------------------------------------------------
extern "C" void kernel_launch(void* const* d_in, const int* in_sizes, int n_in,
                              void* d_out, int out_size, void* d_ws, size_t ws_size,
                              hipStream_t stream) {
    const int* tok = (const int*)d_in[0];
    const int* lens = (const int*)d_in[1];
    const float* emb = (const float*)d_in[2];
    const float* qw = (const float*)d_in[3];
    const float* qb = (const float*)d_in[4];
    const float* kw = (const float*)d_in[5];
    const float* kb = (const float*)d_in[6];
    const float* vw = (const float*)d_in[7];
    const float* vb = (const float*)d_in[8];
    const float* ow = (const float*)d_in[9];
    const float* ob = (const float*)d_in[10];
    const float* relk = (const float*)d_in[11];
    const float* relv = (const float*)d_in[12];
    const float* ln1g = (const float*)d_in[13];
    const float* ln1b = (const float*)d_in[14];
    const float* f1w = (const float*)d_in[15];
    const float* f1b = (const float*)d_in[16];
    const float* f2w = (const float*)d_in[17];
    const float* f2b = (const float*)d_in[18];
    const float* ln2g = (const float*)d_in[19];
    const float* ln2b = (const float*)d_in[20];
    const float* pw = (const float*)d_in[21];
    const float* pb = (const float*)d_in[22];
    const float* eps = (const float*)d_in[23];

    const size_t BHT = (size_t)BN * HN * TN; // 1,572,864
    float* ws = (float*)d_ws;
    float* x = ws;                                   // fp32 ch-major
    float* yf = ws + BHT;                            // fp32 ch-major
    short* s_xb = (short*)(ws + 2 * BHT);            // bf16 t-major (qkv/stats in)
    short* s_ln = (short*)(ws + 2 * BHT + BHT / 2);  // bf16 t-major (f1 in)
    short* s_q  = (short*)(ws + 3 * BHT);
    short* s_k  = (short*)(ws + 3 * BHT + BHT / 2);
    short* s_v  = (short*)(ws + 4 * BHT);
    float* p1   = ws + 3 * BHT;   // f2 partial kg=1 (overlays s_q/s_k: dead by then)
    float* p2   = ws + 4 * BHT;   // f2 partial kg=2 (overlays s_v + free slot)
    short* accP = (short*)(ws + 5 * BHT);            // 4 x BHT shorts (attn partials)
    short* s_y1 = (short*)(ws + 5 * BHT);            // f1 out (B,T,FFN), after attn consumed
    float* stats = ws + 5 * BHT;                     // reused after layers
    short* wqkv = (short*)(ws + 7 * BHT);            // [L][576][192]
    short* wo16 = wqkv + (size_t)LN * 3 * HN * HN;
    short* wp16 = wo16 + (size_t)LN * HN * HN;
    short* wf1_16 = wp16 + (size_t)2 * OUTN * HN;
    short* wf2_16 = wf1_16 + (size_t)LN * 3 * FFNN * HN;
    float* bqkv = (float*)(wf2_16 + (size_t)LN * 3 * FFNN * HN);  // [L][576]
    float* lP = bqkv + (size_t)LN * 576;             // 4 x B x NH x T floats

    // fused weight conversion (single launch)
    {
        long total = (long)LN * 576 * 192 + LN * 576 + LN * HN * HN + 2 * OUTN * HN
                   + 2L * LN * FFNN * HN * 3;
        k_cvtall<<<dim3((unsigned)((total + 255) / 256)), 256, 0, stream>>>(
            qw, kw, vw, qb, kb, vb, ow, pw, f1w, f2w,
            wqkv, bqkv, wo16, wp16, wf1_16, wf2_16);
    }

    dim3 gemb(TN / 64, BN);
    k_embed<<<gemb, 256, 0, stream>>>(tok, lens, emb, x, s_xb);

    dim3 gqkv(TN / 64, 9, BN);          // 16 x 9 x 8
    dim3 gattn(TN / 128, NHN * 4, BN);  // 8 x 8 x 8 (512-thread blocks)
    dim3 goproj(TN / 64, HN / 64, BN);  // 16 x 3 x 8
    dim3 gf1(TN / 128, FFNN / 64, BN);  // 8 x 12 x 8
    dim3 gf2(TN / 128, 9, BN);          // 8 x (3m x 3kg) x 8
    dim3 gln(TN / 32, BN);              // 32 x 8

    for (int i = 0; i < LN; ++i) {
        const short* qkvwi = wqkv + (size_t)i * 576 * 192;
        const float* qkvbi = bqkv + (size_t)i * 576;
        const short* owi = wo16 + (size_t)i * HN * HN;
        const short* f1wi = wf1_16 + (size_t)i * 3 * FFNN * HN;
        const short* f2wi = wf2_16 + (size_t)i * 3 * FFNN * HN;
        const float* obi = ob + (size_t)i * HN;
        const float* rki = relk + (size_t)i * 9 * KCN;
        const float* rvi = relv + (size_t)i * 9 * KCN;
        const float* l1gi = ln1g + (size_t)i * HN;
        const float* l1bi = ln1b + (size_t)i * HN;
        const float* f1bi = f1b + (size_t)i * FFNN;
        const float* f2bi = f2b + (size_t)i * HN;
        const float* l2gi = ln2g + (size_t)i * HN;
        const float* l2bi = ln2b + (size_t)i * HN;

        k_qkv2<<<gqkv, 256, 0, stream>>>(qkvwi, s_xb, qkvbi, s_q, s_k, s_v, lens);
        k_attn4<<<gattn, 512, 0, stream>>>(s_q, s_k, s_v, rki, rvi, accP, lP, lens);
        k_g192<true, false><<<goproj, 256, 0, stream>>>(owi, nullptr, obi, yf, accP, lP, lens, HN);
        k_ln<1><<<gln, 256, 0, stream>>>(x, yf, nullptr, nullptr, l1gi, l1bi, s_ln, lens);
        k_mgemm<3, 128, true, true, 1, 1><<<gf1, 256, 0, stream>>>(f1wi, s_ln, f1bi, s_y1, nullptr, nullptr, lens, FFNN, HN);
        k_mgemm<3, 128, false, true, 0, 3><<<gf2, 256, 0, stream>>>(f2wi, s_y1, f2bi, yf, p1, p2, lens, HN, FFNN);
        k_ln<3><<<gln, 256, 0, stream>>>(x, yf, p1, p2, l2gi, l2bi, s_xb, lens);
    }

    dim3 gstat(TN / 64, (2 * OUTN) / 64, BN); // 16 x 6 x 8
    k_g192<false, true><<<gstat, 256, 0, stream>>>(wp16, s_xb, pb, stats, nullptr, nullptr, lens, 2 * OUTN);
    k_final<<<dim3((unsigned)(BHT / 256)), 256, 0, stream>>>(stats, x, eps, lens, (float*)d_out);
}